// Round 4
// baseline (331.533 us; speedup 1.0000x reference)
//
#include <hip/hip_runtime.h>
#include <math.h>

#define NSAMP 8
#define CH 64
#define HH 64
#define WW 64
#define SPATIAL 4096        // HH*WW
#define PER_SAMPLE 262144   // CH*SPATIAL
#define NTOK 32768          // NSAMP*SPATIAL
#define NHEADS 4
#define HD 16
#define KS 7
#define EPS 1e-5f
#define QSCALE 0.25f        // HD^-0.5

// qkv4 layout: float4 [jg][token], jg = j/4 in [0,48):
//   jg 0-15  : q, head = jg>>2, d4 = jg&3 (pre-scaled by QSCALE)
//   jg 16-31 : k
//   jg 32-47 : v
// y4 layout: float4 [cg][token], cg = c/4 in [0,16)
// token = n*4096 + h*64 + w (lane = w/tok -> coalesced 16B/lane)

__device__ __forceinline__ float dot4(float4 a, float4 b) {
    float s = a.x * b.x;
    s = fmaf(a.y, b.y, s);
    s = fmaf(a.z, b.z, s);
    s = fmaf(a.w, b.w, s);
    return s;
}

// ---------------- K1: per-sample sum / sumsq ----------------
__global__ __launch_bounds__(256) void k_stats(const float* __restrict__ x,
                                               float* __restrict__ stats) {
    int blk = blockIdx.x;           // 256 blocks: 8 samples x 32 chunks
    int n = blk >> 5, chunk = blk & 31;
    const float4* p4 = (const float4*)(x + n * PER_SAMPLE + chunk * 8192);
    int t = threadIdx.x;
    float s1 = 0.f, s2 = 0.f;
#pragma unroll
    for (int i = 0; i < 8; i++) {
        float4 v = p4[t + i * 256];
        s1 += v.x + v.y + v.z + v.w;
        s2 += v.x * v.x + v.y * v.y + v.z * v.z + v.w * v.w;
    }
#pragma unroll
    for (int off = 1; off < 64; off <<= 1) {
        s1 += __shfl_xor(s1, off);
        s2 += __shfl_xor(s2, off);
    }
    __shared__ float r1[4], r2[4];
    int lane = t & 63, wv = t >> 6;
    if (lane == 0) { r1[wv] = s1; r2[wv] = s2; }
    __syncthreads();
    if (t == 0) {
        atomicAdd(&stats[n * 2 + 0], r1[0] + r1[1] + r1[2] + r1[3]);
        atomicAdd(&stats[n * 2 + 1], r2[0] + r2[1] + r2[2] + r2[3]);
    }
}

// ---------------- K2: norm + QKV GEMM -> qkv4 ----------------
// 512 blocks x 512 threads (8 waves): tok = t&63, jg = t>>6 (uniform), 24 rows/thread
__global__ __launch_bounds__(512) void k_qkv(const float* __restrict__ x,
                                             const float* __restrict__ stats,
                                             const float* __restrict__ gn_w,
                                             const float* __restrict__ gn_b,
                                             const float* __restrict__ qkv_w,
                                             const float* __restrict__ qkv_b,
                                             float4* __restrict__ qkv4) {
    int s0 = blockIdx.x * 64;
    int n = s0 >> 12;
    int t = threadIdx.x, tok = t & 63;
    int jg = __builtin_amdgcn_readfirstlane(t >> 6);   // 0..7, wave-uniform
    float mu = stats[2 * n] * (1.f / (float)PER_SAMPLE);
    float var = stats[2 * n + 1] * (1.f / (float)PER_SAMPLE) - mu * mu;
    float rstd = rsqrtf(var + EPS);

    const float* xp = x + n * PER_SAMPLE + (s0 & 4095) + tok;
    float xv[64];
#pragma unroll
    for (int c = 0; c < 64; c++)
        xv[c] = (xp[c * SPATIAL] - mu) * rstd * gn_w[c] + gn_b[c];

#pragma unroll
    for (int kb = 0; kb < 6; kb++) {
        int j = jg * 24 + kb * 4;                       // uniform
        const float4* w0 = (const float4*)(qkv_w + (size_t)(j + 0) * 64);
        const float4* w1 = (const float4*)(qkv_w + (size_t)(j + 1) * 64);
        const float4* w2 = (const float4*)(qkv_w + (size_t)(j + 2) * 64);
        const float4* w3 = (const float4*)(qkv_w + (size_t)(j + 3) * 64);
        float a0 = qkv_b[j], a1 = qkv_b[j + 1], a2 = qkv_b[j + 2], a3 = qkv_b[j + 3];
#pragma unroll
        for (int cg = 0; cg < 16; cg++) {
            float4 xq = ((const float4*)xv)[cg];
            a0 += dot4(xq, w0[cg]);
            a1 += dot4(xq, w1[cg]);
            a2 += dot4(xq, w2[cg]);
            a3 += dot4(xq, w3[cg]);
        }
        if (j < 64) { a0 *= QSCALE; a1 *= QSCALE; a2 *= QSCALE; a3 *= QSCALE; }
        qkv4[(size_t)(j >> 2) * NTOK + s0 + tok] = make_float4(a0, a1, a2, a3);
    }
}

// ---------------- K3: neighborhood attention + proj + residual ----------------
// 512 blocks x 256 threads; wave = head, lane = column
__global__ __launch_bounds__(256) void k_attnproj(const float4* __restrict__ qkv4,
                                                  const float* __restrict__ rpb,
                                                  const float* __restrict__ proj_w,
                                                  const float* __restrict__ proj_b,
                                                  const float* __restrict__ x,
                                                  float4* __restrict__ y4) {
    __shared__ float4 la4[16 * 64];   // attn out [cg][w], 16 KB
    int b = blockIdx.x;               // 512 = 8 samples * 64 rows
    int n = b >> 6, h = b & 63;
    int t = threadIdx.x, w = t & 63;
    int head = __builtin_amdgcn_readfirstlane(t >> 6);
    int rowbase = n * 4096 + h * 64;

    float4 q[4];
#pragma unroll
    for (int i = 0; i < 4; i++)
        q[i] = qkv4[(size_t)(head * 4 + i) * NTOK + rowbase + w];   // coalesced 16B

    int sh = min(max(h - 3, 0), HH - KS);
    int sw = min(max(w - 3, 0), WW - KS);

    float lg[49];
    float mx = -1e30f;
#pragma unroll
    for (int a = 0; a < 7; a++) {
        int nb = n * 4096 + (sh + a) * 64 + sw;
        const float* rp = rpb + (head * 13 + (h - sh + 6 - a)) * 13;
#pragma unroll
        for (int bb = 0; bb < 7; bb++) {
            size_t base = (size_t)(16 + head * 4) * NTOK + nb + bb;
            float4 k0 = qkv4[base];
            float4 k1 = qkv4[base + NTOK];
            float4 k2 = qkv4[base + 2 * NTOK];
            float4 k3 = qkv4[base + 3 * NTOK];
            float d = dot4(q[0], k0) + dot4(q[1], k1) + dot4(q[2], k2) + dot4(q[3], k3);
            d += rp[w - sw + 6 - bb];
            lg[a * 7 + bb] = d;
            mx = fmaxf(mx, d);
        }
    }
    float sum = 0.f;
#pragma unroll
    for (int i = 0; i < 49; i++) {
        float e = __expf(lg[i] - mx);
        lg[i] = e;
        sum += e;
    }
    float rs = 1.f / sum;

    float4 acc[4];
#pragma unroll
    for (int i = 0; i < 4; i++) acc[i] = make_float4(0.f, 0.f, 0.f, 0.f);
#pragma unroll
    for (int a = 0; a < 7; a++) {
        int nb = n * 4096 + (sh + a) * 64 + sw;
#pragma unroll
        for (int bb = 0; bb < 7; bb++) {
            size_t base = (size_t)(32 + head * 4) * NTOK + nb + bb;
            float p = lg[a * 7 + bb];
#pragma unroll
            for (int i = 0; i < 4; i++) {
                float4 v = qkv4[base + (size_t)i * NTOK];
                acc[i].x = fmaf(p, v.x, acc[i].x);
                acc[i].y = fmaf(p, v.y, acc[i].y);
                acc[i].z = fmaf(p, v.z, acc[i].z);
                acc[i].w = fmaf(p, v.w, acc[i].w);
            }
        }
    }
#pragma unroll
    for (int i = 0; i < 4; i++)
        la4[(head * 4 + i) * 64 + w] = make_float4(acc[i].x * rs, acc[i].y * rs,
                                                   acc[i].z * rs, acc[i].w * rs);
    __syncthreads();

    // proj: thread computes 16 output channels (c = head*16 + k) for token w
    float4 av[16];
#pragma unroll
    for (int cg = 0; cg < 16; cg++) av[cg] = la4[cg * 64 + w];

    const float* xr = x + n * PER_SAMPLE + h * 64 + w;
#pragma unroll
    for (int kb = 0; kb < 4; kb++) {
        int c0 = head * 16 + kb * 4;                  // uniform
        const float4* w0 = (const float4*)(proj_w + (size_t)(c0 + 0) * 64);
        const float4* w1 = (const float4*)(proj_w + (size_t)(c0 + 1) * 64);
        const float4* w2 = (const float4*)(proj_w + (size_t)(c0 + 2) * 64);
        const float4* w3 = (const float4*)(proj_w + (size_t)(c0 + 3) * 64);
        float a0 = proj_b[c0], a1 = proj_b[c0 + 1], a2 = proj_b[c0 + 2], a3 = proj_b[c0 + 3];
#pragma unroll
        for (int cg = 0; cg < 16; cg++) {
            float4 aq = av[cg];
            a0 += dot4(aq, w0[cg]);
            a1 += dot4(aq, w1[cg]);
            a2 += dot4(aq, w2[cg]);
            a3 += dot4(aq, w3[cg]);
        }
        a0 += xr[(size_t)(c0 + 0) * SPATIAL];
        a1 += xr[(size_t)(c0 + 1) * SPATIAL];
        a2 += xr[(size_t)(c0 + 2) * SPATIAL];
        a3 += xr[(size_t)(c0 + 3) * SPATIAL];
        y4[(size_t)(head * 4 + kb) * NTOK + rowbase + w] = make_float4(a0, a1, a2, a3);
    }
}

// ---------------- K4: LN + fc1 + GELU + fc2 + residual + NCHW store ----------------
// 512 blocks x 512 threads (8 waves): tok = t&63, g = t>>6 in [0,8)
// yn held in registers (LN replicated per g); LDS only for 64-wide hidden chunks.
__global__ __launch_bounds__(512) void k_mlp(const float4* __restrict__ y4,
                                             const float* __restrict__ ln_w,
                                             const float* __restrict__ ln_b,
                                             const float* __restrict__ fc1_w,
                                             const float* __restrict__ fc1_b,
                                             const float* __restrict__ fc2_w,
                                             const float* __restrict__ fc2_b,
                                             float* __restrict__ out) {
    __shared__ float4 lh4[16 * 64];   // hidden chunk [jg][tok], 16 KB
    int s0 = blockIdx.x * 64;
    int n = s0 >> 12, sp = s0 & 4095;
    int t = threadIdx.x, tok = t & 63;
    int g = __builtin_amdgcn_readfirstlane(t >> 6);   // 0..7, wave-uniform

    // load full token (16 float4), LN computed locally (replicated x8, L1/L2 hits)
    float4 yv[16];
    float s1 = 0.f, s2 = 0.f;
#pragma unroll
    for (int cg = 0; cg < 16; cg++) {
        float4 v = y4[(size_t)cg * NTOK + s0 + tok];
        yv[cg] = v;
        s1 += v.x + v.y + v.z + v.w;
        s2 += v.x * v.x + v.y * v.y + v.z * v.z + v.w * v.w;
    }
    float mu = s1 * (1.f / 64.f);
    float rstd = rsqrtf(s2 * (1.f / 64.f) - mu * mu + EPS);
#pragma unroll
    for (int cg = 0; cg < 16; cg++) {
        float4 wv = ((const float4*)ln_w)[cg];
        float4 bv = ((const float4*)ln_b)[cg];
        yv[cg].x = (yv[cg].x - mu) * rstd * wv.x + bv.x;
        yv[cg].y = (yv[cg].y - mu) * rstd * wv.y + bv.y;
        yv[cg].z = (yv[cg].z - mu) * rstd * wv.z + bv.z;
        yv[cg].w = (yv[cg].w - mu) * rstd * wv.w + bv.w;
    }

    float acc[8];
#pragma unroll
    for (int k = 0; k < 8; k++) acc[k] = 0.f;

    for (int jc = 0; jc < 4; jc++) {
        // phase 1: 8 fc1 rows (two jam-4 groups) for this thread's token
#pragma unroll
        for (int kb = 0; kb < 2; kb++) {
            int j = jc * 64 + g * 8 + kb * 4;          // uniform
            const float4* w0 = (const float4*)(fc1_w + (size_t)(j + 0) * 64);
            const float4* w1 = (const float4*)(fc1_w + (size_t)(j + 1) * 64);
            const float4* w2 = (const float4*)(fc1_w + (size_t)(j + 2) * 64);
            const float4* w3 = (const float4*)(fc1_w + (size_t)(j + 3) * 64);
            float a0 = fc1_b[j], a1 = fc1_b[j + 1], a2 = fc1_b[j + 2], a3 = fc1_b[j + 3];
#pragma unroll
            for (int cg = 0; cg < 16; cg++) {
                float4 yq = yv[cg];
                a0 += dot4(yq, w0[cg]);
                a1 += dot4(yq, w1[cg]);
                a2 += dot4(yq, w2[cg]);
                a3 += dot4(yq, w3[cg]);
            }
            a0 = 0.5f * a0 * (1.f + erff(a0 * 0.70710678118654752f));
            a1 = 0.5f * a1 * (1.f + erff(a1 * 0.70710678118654752f));
            a2 = 0.5f * a2 * (1.f + erff(a2 * 0.70710678118654752f));
            a3 = 0.5f * a3 * (1.f + erff(a3 * 0.70710678118654752f));
            lh4[(g * 2 + kb) * 64 + tok] = make_float4(a0, a1, a2, a3);
        }
        __syncthreads();
        // phase 2: accumulate chunk into 8 output channels (c = g*8 + k)
#pragma unroll
        for (int jg = 0; jg < 16; jg++) {
            float4 hv = lh4[jg * 64 + tok];
#pragma unroll
            for (int k = 0; k < 8; k++) {
                const float4* wr = (const float4*)(fc2_w + (size_t)(g * 8 + k) * 256 + jc * 64 + jg * 4);
                acc[k] += dot4(hv, wr[0]);
            }
        }
        __syncthreads();
    }

    // epilogue: + bias + residual, NCHW coalesced store
    float4 r0 = y4[(size_t)(g * 2 + 0) * NTOK + s0 + tok];
    float4 r1 = y4[(size_t)(g * 2 + 1) * NTOK + s0 + tok];
    float rr[8] = { r0.x, r0.y, r0.z, r0.w, r1.x, r1.y, r1.z, r1.w };
    float* op = out + (size_t)n * PER_SAMPLE + sp + tok;
#pragma unroll
    for (int k = 0; k < 8; k++) {
        int c = g * 8 + k;
        op[(size_t)c * SPATIAL] = acc[k] + fc2_b[c] + rr[k];
    }
}

extern "C" void kernel_launch(void* const* d_in, const int* in_sizes, int n_in,
                              void* d_out, int out_size, void* d_ws, size_t ws_size,
                              hipStream_t stream) {
    const float* x      = (const float*)d_in[0];
    const float* gn_w   = (const float*)d_in[1];
    const float* gn_b   = (const float*)d_in[2];
    const float* qkv_w  = (const float*)d_in[3];
    const float* qkv_b  = (const float*)d_in[4];
    const float* rpb    = (const float*)d_in[5];
    const float* proj_w = (const float*)d_in[6];
    const float* proj_b = (const float*)d_in[7];
    const float* ln_w   = (const float*)d_in[8];
    const float* ln_b   = (const float*)d_in[9];
    const float* fc1_w  = (const float*)d_in[10];
    const float* fc1_b  = (const float*)d_in[11];
    const float* fc2_w  = (const float*)d_in[12];
    const float* fc2_b  = (const float*)d_in[13];
    float* out = (float*)d_out;

    float* ws      = (float*)d_ws;
    float* stats   = ws;                              // 16 floats
    float4* qkv4   = (float4*)(ws + 64);              // 48 * NTOK float4 = 25.2 MB
    float4* y4     = qkv4 + (size_t)48 * NTOK;        // 16 * NTOK float4 = 8.4 MB

    hipMemsetAsync(stats, 0, 64, stream);
    k_stats   <<<256, 256, 0, stream>>>(x, stats);
    k_qkv     <<<512, 512, 0, stream>>>(x, stats, gn_w, gn_b, qkv_w, qkv_b, qkv4);
    k_attnproj<<<512, 256, 0, stream>>>(qkv4, rpb, proj_w, proj_b, x, y4);
    k_mlp     <<<512, 512, 0, stream>>>(y4, ln_w, ln_b, fc1_w, fc1_b, fc2_w, fc2_b, out);
}

// Round 5
// 165.223 us; speedup vs baseline: 2.0066x; 2.0066x over previous
//
#include <hip/hip_runtime.h>
#include <math.h>

#define NSAMP 8
#define CH 64
#define HH 64
#define WW 64
#define SPATIAL 4096        // HH*WW
#define PER_SAMPLE 262144   // CH*SPATIAL
#define NTOK 32768          // NSAMP*SPATIAL
#define NHEADS 4
#define HD 16
#define KS 7
#define EPS 1e-5f
#define QSCALE 0.25f        // HD^-0.5

typedef __attribute__((ext_vector_type(8))) short short8;
typedef __attribute__((ext_vector_type(4))) float f32x4;

__device__ __forceinline__ unsigned short f2bf(float f) {
    unsigned u = __float_as_uint(f);
    u = u + 0x7fffu + ((u >> 16) & 1u);     // round-to-nearest-even
    return (unsigned short)(u >> 16);
}
__device__ __forceinline__ unsigned pack2(float a, float b) {
    return (unsigned)f2bf(a) | ((unsigned)f2bf(b) << 16);
}
__device__ __forceinline__ float dot4(float4 a, float4 b) {
    float s = a.x * b.x;
    s = fmaf(a.y, b.y, s);
    s = fmaf(a.z, b.z, s);
    s = fmaf(a.w, b.w, s);
    return s;
}

// ---------------- K0: weight fp32 -> bf16 ----------------
// wb layout: [0,12288) qkv_w | [12288,28672) fc1_w | [28672,45056) fc2_w
__global__ __launch_bounds__(256) void k_prep(const float* __restrict__ qkv_w,
                                              const float* __restrict__ fc1_w,
                                              const float* __restrict__ fc2_w,
                                              unsigned short* __restrict__ wb) {
    int i = blockIdx.x * 256 + threadIdx.x;
    if (i < 12288)      wb[i] = f2bf(qkv_w[i]);
    else if (i < 28672) wb[i] = f2bf(fc1_w[i - 12288]);
    else if (i < 45056) wb[i] = f2bf(fc2_w[i - 28672]);
}

// ---------------- K1: per-sample sum / sumsq ----------------
__global__ __launch_bounds__(256) void k_stats(const float* __restrict__ x,
                                               float* __restrict__ stats) {
    int blk = blockIdx.x;           // 256 blocks: 8 samples x 32 chunks
    int n = blk >> 5, chunk = blk & 31;
    const float4* p4 = (const float4*)(x + n * PER_SAMPLE + chunk * 8192);
    int t = threadIdx.x;
    float s1 = 0.f, s2 = 0.f;
#pragma unroll
    for (int i = 0; i < 8; i++) {
        float4 v = p4[t + i * 256];
        s1 += v.x + v.y + v.z + v.w;
        s2 += v.x * v.x + v.y * v.y + v.z * v.z + v.w * v.w;
    }
#pragma unroll
    for (int off = 1; off < 64; off <<= 1) {
        s1 += __shfl_xor(s1, off);
        s2 += __shfl_xor(s2, off);
    }
    __shared__ float r1[4], r2[4];
    int lane = t & 63, wv = t >> 6;
    if (lane == 0) { r1[wv] = s1; r2[wv] = s2; }
    __syncthreads();
    if (t == 0) {
        atomicAdd(&stats[n * 2 + 0], r1[0] + r1[1] + r1[2] + r1[3]);
        atomicAdd(&stats[n * 2 + 1], r2[0] + r2[1] + r2[2] + r2[3]);
    }
}

// ---------------- K2: GN + QKV GEMM via MFMA -> qkv4 (fp32 channel-group-major) ----------------
// 512 blocks x 256 threads (4 waves). Block = 64 tokens. M=64, N=192, K=64.
__global__ __launch_bounds__(256) void k_qkv(const float* __restrict__ x,
                                             const float* __restrict__ stats,
                                             const float* __restrict__ gn_w,
                                             const float* __restrict__ gn_b,
                                             const unsigned short* __restrict__ qkv_wb,
                                             const float* __restrict__ qkv_b,
                                             float4* __restrict__ qkv4) {
    __shared__ __attribute__((aligned(16))) short xA[4 * 2 * 64 * 8];  // 8 KB frag-major A
    __shared__ float obuf[4][16 * 65];                                 // per-wave transpose
    int s0 = blockIdx.x * 64;
    int smp = s0 >> 12, sp = s0 & 4095;
    int t = threadIdx.x, tok = t & 63, g = t >> 6;

    float mu = stats[2 * smp] * (1.f / (float)PER_SAMPLE);
    float var = stats[2 * smp + 1] * (1.f / (float)PER_SAMPLE) - mu * mu;
    float rstd = rsqrtf(var + EPS);

    // stage A: thread owns channels g*16..g*16+15 of token tok
    {
        const float* xp = x + smp * PER_SAMPLE + sp + tok;
        float v[16];
#pragma unroll
        for (int i = 0; i < 16; i++) {
            int c = g * 16 + i;
            v[i] = (xp[(size_t)c * SPATIAL] - mu) * rstd * gn_w[c] + gn_b[c];
        }
#pragma unroll
        for (int e = 0; e < 2; e++) {
            int cb = 2 * g + e;                // 8-ch block, c = cb*8..cb*8+7
            int kf = cb >> 2, qq = cb & 3;
            uint4 p;
            p.x = pack2(v[e * 8 + 0], v[e * 8 + 1]);
            p.y = pack2(v[e * 8 + 2], v[e * 8 + 3]);
            p.z = pack2(v[e * 8 + 4], v[e * 8 + 5]);
            p.w = pack2(v[e * 8 + 6], v[e * 8 + 7]);
            int chunk = ((tok >> 4) * 2 + kf) * 64 + (tok & 15) + (qq << 4);
            *(uint4*)&xA[chunk * 8] = p;
        }
    }
    __syncthreads();

    int w = __builtin_amdgcn_readfirstlane(g);
    int lane = t & 63, nh = lane & 15, q = lane >> 4;

    // preload 8 A-frags (mt x kf)
    short8 af[8];
#pragma unroll
    for (int mt = 0; mt < 4; mt++)
#pragma unroll
        for (int kf = 0; kf < 2; kf++)
            af[mt * 2 + kf] = *(const short8*)&xA[((mt * 2 + kf) * 64 + lane) * 8];

    for (int nt = 0; nt < 3; nt++) {
        int n0 = w * 48 + nt * 16;
        const unsigned short* wp = qkv_wb + (size_t)(n0 + nh) * 64 + q * 8;
        short8 b0 = *(const short8*)(wp);
        short8 b1 = *(const short8*)(wp + 32);
        float bias = qkv_b[n0 + nh];
        bool isq = (n0 < 64);
        f32x4 acc[4];
#pragma unroll
        for (int mt = 0; mt < 4; mt++) {
            f32x4 d = {0.f, 0.f, 0.f, 0.f};
            d = __builtin_amdgcn_mfma_f32_16x16x32_bf16(af[mt * 2 + 0], b0, d, 0, 0, 0);
            d = __builtin_amdgcn_mfma_f32_16x16x32_bf16(af[mt * 2 + 1], b1, d, 0, 0, 0);
            acc[mt] = d;
        }
#pragma unroll
        for (int mt = 0; mt < 4; mt++)
#pragma unroll
            for (int r = 0; r < 4; r++) {
                float vv = acc[mt][r] + bias;
                if (isq) vv *= QSCALE;
                obuf[w][nh * 65 + mt * 16 + q * 4 + r] = vv;
            }
        __syncthreads();
#pragma unroll
        for (int u = 0; u < 4; u++) {
            int cg = (n0 >> 2) + u;
            float4 o;
            o.x = obuf[w][(u * 4 + 0) * 65 + lane];
            o.y = obuf[w][(u * 4 + 1) * 65 + lane];
            o.z = obuf[w][(u * 4 + 2) * 65 + lane];
            o.w = obuf[w][(u * 4 + 3) * 65 + lane];
            qkv4[(size_t)cg * NTOK + s0 + lane] = o;
        }
        __syncthreads();
    }
}

// ---------------- K3: neighborhood attention + proj + residual (UNCHANGED from R4) ----------------
__global__ __launch_bounds__(256) void k_attnproj(const float4* __restrict__ qkv4,
                                                  const float* __restrict__ rpb,
                                                  const float* __restrict__ proj_w,
                                                  const float* __restrict__ proj_b,
                                                  const float* __restrict__ x,
                                                  float4* __restrict__ y4) {
    __shared__ float4 la4[16 * 64];   // attn out [cg][w], 16 KB
    int b = blockIdx.x;               // 512 = 8 samples * 64 rows
    int n = b >> 6, h = b & 63;
    int t = threadIdx.x, w = t & 63;
    int head = __builtin_amdgcn_readfirstlane(t >> 6);
    int rowbase = n * 4096 + h * 64;

    float4 q[4];
#pragma unroll
    for (int i = 0; i < 4; i++)
        q[i] = qkv4[(size_t)(head * 4 + i) * NTOK + rowbase + w];

    int sh = min(max(h - 3, 0), HH - KS);
    int sw = min(max(w - 3, 0), WW - KS);

    float lg[49];
    float mx = -1e30f;
#pragma unroll
    for (int a = 0; a < 7; a++) {
        int nb = n * 4096 + (sh + a) * 64 + sw;
        const float* rp = rpb + (head * 13 + (h - sh + 6 - a)) * 13;
#pragma unroll
        for (int bb = 0; bb < 7; bb++) {
            size_t base = (size_t)(16 + head * 4) * NTOK + nb + bb;
            float4 k0 = qkv4[base];
            float4 k1 = qkv4[base + NTOK];
            float4 k2 = qkv4[base + 2 * NTOK];
            float4 k3 = qkv4[base + 3 * NTOK];
            float d = dot4(q[0], k0) + dot4(q[1], k1) + dot4(q[2], k2) + dot4(q[3], k3);
            d += rp[w - sw + 6 - bb];
            lg[a * 7 + bb] = d;
            mx = fmaxf(mx, d);
        }
    }
    float sum = 0.f;
#pragma unroll
    for (int i = 0; i < 49; i++) {
        float e = __expf(lg[i] - mx);
        lg[i] = e;
        sum += e;
    }
    float rs = 1.f / sum;

    float4 acc[4];
#pragma unroll
    for (int i = 0; i < 4; i++) acc[i] = make_float4(0.f, 0.f, 0.f, 0.f);
#pragma unroll
    for (int a = 0; a < 7; a++) {
        int nb = n * 4096 + (sh + a) * 64 + sw;
#pragma unroll
        for (int bb = 0; bb < 7; bb++) {
            size_t base = (size_t)(32 + head * 4) * NTOK + nb + bb;
            float p = lg[a * 7 + bb];
#pragma unroll
            for (int i = 0; i < 4; i++) {
                float4 v = qkv4[base + (size_t)i * NTOK];
                acc[i].x = fmaf(p, v.x, acc[i].x);
                acc[i].y = fmaf(p, v.y, acc[i].y);
                acc[i].z = fmaf(p, v.z, acc[i].z);
                acc[i].w = fmaf(p, v.w, acc[i].w);
            }
        }
    }
#pragma unroll
    for (int i = 0; i < 4; i++)
        la4[(head * 4 + i) * 64 + w] = make_float4(acc[i].x * rs, acc[i].y * rs,
                                                   acc[i].z * rs, acc[i].w * rs);
    __syncthreads();

    float4 av[16];
#pragma unroll
    for (int cg = 0; cg < 16; cg++) av[cg] = la4[cg * 64 + w];

    const float* xr = x + n * PER_SAMPLE + h * 64 + w;
#pragma unroll
    for (int kb = 0; kb < 4; kb++) {
        int c0 = head * 16 + kb * 4;
        const float4* w0 = (const float4*)(proj_w + (size_t)(c0 + 0) * 64);
        const float4* w1 = (const float4*)(proj_w + (size_t)(c0 + 1) * 64);
        const float4* w2 = (const float4*)(proj_w + (size_t)(c0 + 2) * 64);
        const float4* w3 = (const float4*)(proj_w + (size_t)(c0 + 3) * 64);
        float a0 = proj_b[c0], a1 = proj_b[c0 + 1], a2 = proj_b[c0 + 2], a3 = proj_b[c0 + 3];
#pragma unroll
        for (int cg = 0; cg < 16; cg++) {
            float4 aq = av[cg];
            a0 += dot4(aq, w0[cg]);
            a1 += dot4(aq, w1[cg]);
            a2 += dot4(aq, w2[cg]);
            a3 += dot4(aq, w3[cg]);
        }
        a0 += xr[(size_t)(c0 + 0) * SPATIAL];
        a1 += xr[(size_t)(c0 + 1) * SPATIAL];
        a2 += xr[(size_t)(c0 + 2) * SPATIAL];
        a3 += xr[(size_t)(c0 + 3) * SPATIAL];
        y4[(size_t)(head * 4 + kb) * NTOK + rowbase + w] = make_float4(a0, a1, a2, a3);
    }
}

// ---------------- K4: LN + fc1 + GELU + fc2 + residual via MFMA ----------------
// 512 blocks x 256 threads (4 waves). Block = 64 tokens. fc1: 64x256 K=64; fc2: 64x64 K=256.
__global__ __launch_bounds__(256) void k_mlp(const float4* __restrict__ y4,
                                             const float* __restrict__ ln_w,
                                             const float* __restrict__ ln_b,
                                             const unsigned short* __restrict__ fc1_wb,
                                             const float* __restrict__ fc1_b,
                                             const unsigned short* __restrict__ fc2_wb,
                                             const float* __restrict__ fc2_b,
                                             float* __restrict__ out) {
    __shared__ __attribute__((aligned(16))) short ynA[4 * 2 * 64 * 8];  // 8 KB  (fc1 A-frags)
    __shared__ __attribute__((aligned(16))) short lhA[4 * 8 * 64 * 8];  // 32 KB (fc2 A-frags)
    __shared__ float obuf[4][16 * 65];                                  // 16.6 KB
    __shared__ float red1[256], red2[256];
    int s0 = blockIdx.x * 64;
    int smp = s0 >> 12, sp = s0 & 4095;
    int t = threadIdx.x, tok = t & 63, g = t >> 6;

    // --- LN: thread owns channels g*16..+15 of token tok ---
    float v[16];
    float s1 = 0.f, s2 = 0.f;
#pragma unroll
    for (int i = 0; i < 4; i++) {
        float4 yy = y4[(size_t)(g * 4 + i) * NTOK + s0 + tok];
        v[i * 4 + 0] = yy.x; v[i * 4 + 1] = yy.y; v[i * 4 + 2] = yy.z; v[i * 4 + 3] = yy.w;
        s1 += yy.x + yy.y + yy.z + yy.w;
        s2 += yy.x * yy.x + yy.y * yy.y + yy.z * yy.z + yy.w * yy.w;
    }
    red1[g * 64 + tok] = s1;
    red2[g * 64 + tok] = s2;
    __syncthreads();
    float mu = (red1[tok] + red1[64 + tok] + red1[128 + tok] + red1[192 + tok]) * (1.f / 64.f);
    float sq = (red2[tok] + red2[64 + tok] + red2[128 + tok] + red2[192 + tok]) * (1.f / 64.f);
    float rstd = rsqrtf(sq - mu * mu + EPS);
#pragma unroll
    for (int i = 0; i < 16; i++) {
        int c = g * 16 + i;
        v[i] = (v[i] - mu) * rstd * ln_w[c] + ln_b[c];
    }
#pragma unroll
    for (int e = 0; e < 2; e++) {
        int cb = 2 * g + e;
        int kf = cb >> 2, qq = cb & 3;
        uint4 p;
        p.x = pack2(v[e * 8 + 0], v[e * 8 + 1]);
        p.y = pack2(v[e * 8 + 2], v[e * 8 + 3]);
        p.z = pack2(v[e * 8 + 4], v[e * 8 + 5]);
        p.w = pack2(v[e * 8 + 6], v[e * 8 + 7]);
        int chunk = ((tok >> 4) * 2 + kf) * 64 + (tok & 15) + (qq << 4);
        *(uint4*)&ynA[chunk * 8] = p;
    }
    __syncthreads();

    int w = __builtin_amdgcn_readfirstlane(g);
    int lane = t & 63, nh = lane & 15, q = lane >> 4;

    // --- fc1 + GELU -> lhA (fc2 A-frag layout) ---
    {
        short8 af[8];
#pragma unroll
        for (int mt = 0; mt < 4; mt++)
#pragma unroll
            for (int kf = 0; kf < 2; kf++)
                af[mt * 2 + kf] = *(const short8*)&ynA[((mt * 2 + kf) * 64 + lane) * 8];

        for (int nt = 0; nt < 4; nt++) {
            int n0 = w * 64 + nt * 16;
            const unsigned short* wp = fc1_wb + (size_t)(n0 + nh) * 64 + q * 8;
            short8 b0 = *(const short8*)(wp);
            short8 b1 = *(const short8*)(wp + 32);
            float bias = fc1_b[n0 + nh];
            int j = n0 + nh;                      // this lane's hidden index
            int kf2 = j >> 5, q2 = (j >> 3) & 3, jb = j & 7;
#pragma unroll
            for (int mt = 0; mt < 4; mt++) {
                f32x4 d = {0.f, 0.f, 0.f, 0.f};
                d = __builtin_amdgcn_mfma_f32_16x16x32_bf16(af[mt * 2 + 0], b0, d, 0, 0, 0);
                d = __builtin_amdgcn_mfma_f32_16x16x32_bf16(af[mt * 2 + 1], b1, d, 0, 0, 0);
#pragma unroll
                for (int r = 0; r < 4; r++) {
                    float hv = d[r] + bias;
                    hv = 0.5f * hv * (1.f + erff(hv * 0.70710678118654752f));
                    // element (m = mt*16 + q*4 + r, k = j) in fc2 A-frag layout
                    lhA[(mt * 8 + kf2) * 512 + ((q * 4 + r) + (q2 << 4)) * 8 + jb] = (short)f2bf(hv);
                }
            }
        }
    }
    __syncthreads();

    // --- fc2: strip n0 = w*16, K=256 ---
    {
        int n0 = w * 16;
        f32x4 acc[4];
#pragma unroll
        for (int mt = 0; mt < 4; mt++) acc[mt] = (f32x4){0.f, 0.f, 0.f, 0.f};
#pragma unroll
        for (int kf = 0; kf < 8; kf++) {
            const unsigned short* wp = fc2_wb + (size_t)(n0 + nh) * 256 + kf * 32 + q * 8;
            short8 b = *(const short8*)(wp);
#pragma unroll
            for (int mt = 0; mt < 4; mt++) {
                short8 a = *(const short8*)&lhA[((mt * 8 + kf) * 64 + lane) * 8];
                acc[mt] = __builtin_amdgcn_mfma_f32_16x16x32_bf16(a, b, acc[mt], 0, 0, 0);
            }
        }
#pragma unroll
        for (int mt = 0; mt < 4; mt++)
#pragma unroll
            for (int r = 0; r < 4; r++)
                obuf[w][nh * 65 + mt * 16 + q * 4 + r] = acc[mt][r];
        __syncthreads();

        // store: + fc2_b + residual, NCHW coalesced
        float* op = out + (size_t)smp * PER_SAMPLE + sp;
#pragma unroll
        for (int u = 0; u < 4; u++) {
            int cg = (n0 >> 2) + u;
            float4 res = y4[(size_t)cg * NTOK + s0 + lane];
            float rr[4] = {res.x, res.y, res.z, res.w};
#pragma unroll
            for (int e = 0; e < 4; e++) {
                int c = cg * 4 + e;
                op[(size_t)c * SPATIAL + lane] = obuf[w][(u * 4 + e) * 65 + lane] + fc2_b[c] + rr[e];
            }
        }
    }
}

extern "C" void kernel_launch(void* const* d_in, const int* in_sizes, int n_in,
                              void* d_out, int out_size, void* d_ws, size_t ws_size,
                              hipStream_t stream) {
    const float* x      = (const float*)d_in[0];
    const float* gn_w   = (const float*)d_in[1];
    const float* gn_b   = (const float*)d_in[2];
    const float* qkv_w  = (const float*)d_in[3];
    const float* qkv_b  = (const float*)d_in[4];
    const float* rpb    = (const float*)d_in[5];
    const float* proj_w = (const float*)d_in[6];
    const float* proj_b = (const float*)d_in[7];
    const float* ln_w   = (const float*)d_in[8];
    const float* ln_b   = (const float*)d_in[9];
    const float* fc1_w  = (const float*)d_in[10];
    const float* fc1_b  = (const float*)d_in[11];
    const float* fc2_w  = (const float*)d_in[12];
    const float* fc2_b  = (const float*)d_in[13];
    float* out = (float*)d_out;

    float* ws      = (float*)d_ws;
    float* stats   = ws;                              // 16 floats
    float4* qkv4   = (float4*)(ws + 64);              // 48 * NTOK float4 = 25.2 MB
    float4* y4     = qkv4 + (size_t)48 * NTOK;        // 16 * NTOK float4 = 8.4 MB
    unsigned short* wb = (unsigned short*)(y4 + (size_t)16 * NTOK);   // 45056 bf16 = 90 KB
    unsigned short* qkv_wb = wb;
    unsigned short* fc1_wb = wb + 12288;
    unsigned short* fc2_wb = wb + 28672;

    hipMemsetAsync(stats, 0, 64, stream);
    k_prep    <<<176, 256, 0, stream>>>(qkv_w, fc1_w, fc2_w, wb);
    k_stats   <<<256, 256, 0, stream>>>(x, stats);
    k_qkv     <<<512, 256, 0, stream>>>(x, stats, gn_w, gn_b, qkv_wb, qkv_b, qkv4);
    k_attnproj<<<512, 256, 0, stream>>>(qkv4, rpb, proj_w, proj_b, x, y4);
    k_mlp     <<<512, 256, 0, stream>>>(y4, ln_w, ln_b, fc1_wb, fc1_b, fc2_wb, fc2_b, out);
}

// Round 6
// 137.500 us; speedup vs baseline: 2.4111x; 1.2016x over previous
//
#include <hip/hip_runtime.h>
#include <math.h>

#define NSAMP 8
#define CH 64
#define HH 64
#define WW 64
#define SPATIAL 4096        // HH*WW
#define PER_SAMPLE 262144   // CH*SPATIAL
#define NTOK 32768          // NSAMP*SPATIAL
#define NHEADS 4
#define HD 16
#define KS 7
#define EPS 1e-5f
#define QSCALE 0.25f        // HD^-0.5

typedef __attribute__((ext_vector_type(8))) short short8;
typedef __attribute__((ext_vector_type(4))) float f32x4;

__device__ __forceinline__ unsigned short f2bf(float f) {
    unsigned u = __float_as_uint(f);
    u = u + 0x7fffu + ((u >> 16) & 1u);     // round-to-nearest-even
    return (unsigned short)(u >> 16);
}
__device__ __forceinline__ unsigned pack2(float a, float b) {
    return (unsigned)f2bf(a) | ((unsigned)f2bf(b) << 16);
}
// dot of 8 packed bf16 channels against fp32 q[0..7]
__device__ __forceinline__ float dot8_bf(uint4 u, const float* qv) {
    float s;
    s = __uint_as_float(u.x << 16) * qv[0];
    s = fmaf(__uint_as_float(u.x & 0xffff0000u), qv[1], s);
    s = fmaf(__uint_as_float(u.y << 16),         qv[2], s);
    s = fmaf(__uint_as_float(u.y & 0xffff0000u), qv[3], s);
    s = fmaf(__uint_as_float(u.z << 16),         qv[4], s);
    s = fmaf(__uint_as_float(u.z & 0xffff0000u), qv[5], s);
    s = fmaf(__uint_as_float(u.w << 16),         qv[6], s);
    s = fmaf(__uint_as_float(u.w & 0xffff0000u), qv[7], s);
    return s;
}
__device__ __forceinline__ void pv8_bf(uint4 u, float p, float* acc) {
    acc[0] = fmaf(p, __uint_as_float(u.x << 16),         acc[0]);
    acc[1] = fmaf(p, __uint_as_float(u.x & 0xffff0000u), acc[1]);
    acc[2] = fmaf(p, __uint_as_float(u.y << 16),         acc[2]);
    acc[3] = fmaf(p, __uint_as_float(u.y & 0xffff0000u), acc[3]);
    acc[4] = fmaf(p, __uint_as_float(u.z << 16),         acc[4]);
    acc[5] = fmaf(p, __uint_as_float(u.z & 0xffff0000u), acc[5]);
    acc[6] = fmaf(p, __uint_as_float(u.w << 16),         acc[6]);
    acc[7] = fmaf(p, __uint_as_float(u.w & 0xffff0000u), acc[7]);
}

// ---------------- K0: weight fp32 -> bf16 ----------------
// wb: [0,12288) qkv_w | [12288,28672) fc1_w | [28672,45056) fc2_w | [45056,49152) proj_w
__global__ __launch_bounds__(256) void k_prep(const float* __restrict__ qkv_w,
                                              const float* __restrict__ fc1_w,
                                              const float* __restrict__ fc2_w,
                                              const float* __restrict__ proj_w,
                                              unsigned short* __restrict__ wb) {
    int i = blockIdx.x * 256 + threadIdx.x;
    if (i < 12288)      wb[i] = f2bf(qkv_w[i]);
    else if (i < 28672) wb[i] = f2bf(fc1_w[i - 12288]);
    else if (i < 45056) wb[i] = f2bf(fc2_w[i - 28672]);
    else if (i < 49152) wb[i] = f2bf(proj_w[i - 45056]);
}

// ---------------- K1: per-sample sum / sumsq ----------------
__global__ __launch_bounds__(256) void k_stats(const float* __restrict__ x,
                                               float* __restrict__ stats) {
    int blk = blockIdx.x;           // 256 blocks: 8 samples x 32 chunks
    int n = blk >> 5, chunk = blk & 31;
    const float4* p4 = (const float4*)(x + n * PER_SAMPLE + chunk * 8192);
    int t = threadIdx.x;
    float s1 = 0.f, s2 = 0.f;
#pragma unroll
    for (int i = 0; i < 8; i++) {
        float4 v = p4[t + i * 256];
        s1 += v.x + v.y + v.z + v.w;
        s2 += v.x * v.x + v.y * v.y + v.z * v.z + v.w * v.w;
    }
#pragma unroll
    for (int off = 1; off < 64; off <<= 1) {
        s1 += __shfl_xor(s1, off);
        s2 += __shfl_xor(s2, off);
    }
    __shared__ float r1[4], r2[4];
    int lane = t & 63, wv = t >> 6;
    if (lane == 0) { r1[wv] = s1; r2[wv] = s2; }
    __syncthreads();
    if (t == 0) {
        atomicAdd(&stats[n * 2 + 0], r1[0] + r1[1] + r1[2] + r1[3]);
        atomicAdd(&stats[n * 2 + 1], r2[0] + r2[1] + r2[2] + r2[3]);
    }
}

// ---------------- K2: GN + QKV GEMM via MFMA -> bf16 q / kv ----------------
// 512 blocks x 256 threads (4 waves). Block = 64 tokens. M=64, N=192, K=64.
// qb8 : uint4 [g8][token], g8 in [0,8)  = q channels g8*8..+7 (pre-scaled)
// kvb8: uint4 [g8][token], g8 in [0,16) = k (0-7) then v (8-15)
__global__ __launch_bounds__(256) void k_qkv(const float* __restrict__ x,
                                             const float* __restrict__ stats,
                                             const float* __restrict__ gn_w,
                                             const float* __restrict__ gn_b,
                                             const unsigned short* __restrict__ qkv_wb,
                                             const float* __restrict__ qkv_b,
                                             uint4* __restrict__ qb8,
                                             uint4* __restrict__ kvb8) {
    __shared__ __attribute__((aligned(16))) short xA[4 * 2 * 64 * 8];  // 8 KB frag-major A
    __shared__ float obuf[4][16 * 65];                                 // per-wave transpose
    int s0 = blockIdx.x * 64;
    int smp = s0 >> 12, sp = s0 & 4095;
    int t = threadIdx.x, tok = t & 63, g = t >> 6;

    float mu = stats[2 * smp] * (1.f / (float)PER_SAMPLE);
    float var = stats[2 * smp + 1] * (1.f / (float)PER_SAMPLE) - mu * mu;
    float rstd = rsqrtf(var + EPS);

    // stage A: thread owns channels g*16..g*16+15 of token tok
    {
        const float* xp = x + smp * PER_SAMPLE + sp + tok;
        float v[16];
#pragma unroll
        for (int i = 0; i < 16; i++) {
            int c = g * 16 + i;
            v[i] = (xp[(size_t)c * SPATIAL] - mu) * rstd * gn_w[c] + gn_b[c];
        }
#pragma unroll
        for (int e = 0; e < 2; e++) {
            int cb = 2 * g + e;                // 8-ch block
            int kf = cb >> 2, qq = cb & 3;
            uint4 p;
            p.x = pack2(v[e * 8 + 0], v[e * 8 + 1]);
            p.y = pack2(v[e * 8 + 2], v[e * 8 + 3]);
            p.z = pack2(v[e * 8 + 4], v[e * 8 + 5]);
            p.w = pack2(v[e * 8 + 6], v[e * 8 + 7]);
            int chunk = ((tok >> 4) * 2 + kf) * 64 + (tok & 15) + (qq << 4);
            *(uint4*)&xA[chunk * 8] = p;
        }
    }
    __syncthreads();

    int w = __builtin_amdgcn_readfirstlane(g);
    int lane = t & 63, nh = lane & 15, qd = lane >> 4;

    short8 af[8];
#pragma unroll
    for (int mt = 0; mt < 4; mt++)
#pragma unroll
        for (int kf = 0; kf < 2; kf++)
            af[mt * 2 + kf] = *(const short8*)&xA[((mt * 2 + kf) * 64 + lane) * 8];

    for (int nt = 0; nt < 3; nt++) {
        int n0 = w * 48 + nt * 16;
        const unsigned short* wp = qkv_wb + (size_t)(n0 + nh) * 64 + qd * 8;
        short8 b0 = *(const short8*)(wp);
        short8 b1 = *(const short8*)(wp + 32);
        float bias = qkv_b[n0 + nh];
        bool isq = (n0 < 64);
        f32x4 acc[4];
#pragma unroll
        for (int mt = 0; mt < 4; mt++) {
            f32x4 d = {0.f, 0.f, 0.f, 0.f};
            d = __builtin_amdgcn_mfma_f32_16x16x32_bf16(af[mt * 2 + 0], b0, d, 0, 0, 0);
            d = __builtin_amdgcn_mfma_f32_16x16x32_bf16(af[mt * 2 + 1], b1, d, 0, 0, 0);
            acc[mt] = d;
        }
#pragma unroll
        for (int mt = 0; mt < 4; mt++)
#pragma unroll
            for (int r = 0; r < 4; r++) {
                float vv = acc[mt][r] + bias;
                if (isq) vv *= QSCALE;
                obuf[w][nh * 65 + mt * 16 + qd * 4 + r] = vv;
            }
        __syncthreads();
        // pack strip (16 ch x 64 tok) -> 2 x ushort8 per lane, bf16 stores
#pragma unroll
        for (int u = 0; u < 2; u++) {
            uint4 p;
            p.x = pack2(obuf[w][(u * 8 + 0) * 65 + lane], obuf[w][(u * 8 + 1) * 65 + lane]);
            p.y = pack2(obuf[w][(u * 8 + 2) * 65 + lane], obuf[w][(u * 8 + 3) * 65 + lane]);
            p.z = pack2(obuf[w][(u * 8 + 4) * 65 + lane], obuf[w][(u * 8 + 5) * 65 + lane]);
            p.w = pack2(obuf[w][(u * 8 + 6) * 65 + lane], obuf[w][(u * 8 + 7) * 65 + lane]);
            if (n0 < 64)
                qb8[(size_t)((n0 >> 3) + u) * NTOK + s0 + lane] = p;
            else if (n0 < 128)
                kvb8[(size_t)(((n0 - 64) >> 3) + u) * NTOK + s0 + lane] = p;
            else
                kvb8[(size_t)(8 + ((n0 - 128) >> 3) + u) * NTOK + s0 + lane] = p;
        }
        __syncthreads();
    }
}

// ---------------- K3: neighborhood attention (bf16 gather) + proj MFMA + residual ----------------
// 512 blocks x 256 threads; wave = head, lane = column
__global__ __launch_bounds__(256) void k_attnproj(const uint4* __restrict__ qb8,
                                                  const uint4* __restrict__ kvb8,
                                                  const float* __restrict__ rpb,
                                                  const unsigned short* __restrict__ proj_wb,
                                                  const float* __restrict__ proj_b,
                                                  const float* __restrict__ x,
                                                  float4* __restrict__ y4) {
    __shared__ __attribute__((aligned(16))) short xA[4 * 2 * 64 * 8];  // 8 KB frag-major A
    __shared__ float obuf[4][16 * 65];
    int b = blockIdx.x;               // 512 = 8 samples * 64 rows
    int n = b >> 6, h = b & 63;
    int t = threadIdx.x, w = t & 63;
    int head = __builtin_amdgcn_readfirstlane(t >> 6);
    int rowbase = n * 4096 + h * 64;

    float q[16];
    {
        uint4 qa = qb8[(size_t)(2 * head) * NTOK + rowbase + w];
        uint4 qc = qb8[(size_t)(2 * head + 1) * NTOK + rowbase + w];
        q[0] = __uint_as_float(qa.x << 16); q[1] = __uint_as_float(qa.x & 0xffff0000u);
        q[2] = __uint_as_float(qa.y << 16); q[3] = __uint_as_float(qa.y & 0xffff0000u);
        q[4] = __uint_as_float(qa.z << 16); q[5] = __uint_as_float(qa.z & 0xffff0000u);
        q[6] = __uint_as_float(qa.w << 16); q[7] = __uint_as_float(qa.w & 0xffff0000u);
        q[8]  = __uint_as_float(qc.x << 16); q[9]  = __uint_as_float(qc.x & 0xffff0000u);
        q[10] = __uint_as_float(qc.y << 16); q[11] = __uint_as_float(qc.y & 0xffff0000u);
        q[12] = __uint_as_float(qc.z << 16); q[13] = __uint_as_float(qc.z & 0xffff0000u);
        q[14] = __uint_as_float(qc.w << 16); q[15] = __uint_as_float(qc.w & 0xffff0000u);
    }
    int sh = min(max(h - 3, 0), HH - KS);
    int sw = min(max(w - 3, 0), WW - KS);

    float lg[49];
    float mx = -1e30f;
#pragma unroll
    for (int a = 0; a < 7; a++) {
        int nb = n * 4096 + (sh + a) * 64 + sw;
        const float* rp = rpb + (head * 13 + (h - sh + 6 - a)) * 13;
#pragma unroll
        for (int bb = 0; bb < 7; bb++) {
            size_t base = (size_t)(2 * head) * NTOK + nb + bb;
            float d = dot8_bf(kvb8[base], q) + dot8_bf(kvb8[base + NTOK], q + 8);
            d += rp[w - sw + 6 - bb];
            lg[a * 7 + bb] = d;
            mx = fmaxf(mx, d);
        }
    }
    float sum = 0.f;
#pragma unroll
    for (int i = 0; i < 49; i++) {
        float e = __expf(lg[i] - mx);
        lg[i] = e;
        sum += e;
    }
    float rs = 1.f / sum;

    float acc[16];
#pragma unroll
    for (int i = 0; i < 16; i++) acc[i] = 0.f;
#pragma unroll
    for (int a = 0; a < 7; a++) {
        int nb = n * 4096 + (sh + a) * 64 + sw;
#pragma unroll
        for (int bb = 0; bb < 7; bb++) {
            size_t base = (size_t)(8 + 2 * head) * NTOK + nb + bb;
            float p = lg[a * 7 + bb];
            pv8_bf(kvb8[base], p, acc);
            pv8_bf(kvb8[base + NTOK], p, acc + 8);
        }
    }

    // stage attn-out (x rs) as bf16 A-frags: thread owns ch head*16..+15 of token w
#pragma unroll
    for (int e = 0; e < 2; e++) {
        int cb = 2 * head + e;
        int kf = cb >> 2, qq = cb & 3;
        uint4 p;
        p.x = pack2(acc[e * 8 + 0] * rs, acc[e * 8 + 1] * rs);
        p.y = pack2(acc[e * 8 + 2] * rs, acc[e * 8 + 3] * rs);
        p.z = pack2(acc[e * 8 + 4] * rs, acc[e * 8 + 5] * rs);
        p.w = pack2(acc[e * 8 + 6] * rs, acc[e * 8 + 7] * rs);
        int chunk = ((w >> 4) * 2 + kf) * 64 + (w & 15) + (qq << 4);
        *(uint4*)&xA[chunk * 8] = p;
    }
    __syncthreads();

    // proj MFMA: wave strip n0 = head*16, M=64 tokens, K=64
    int lane = t & 63, nh = lane & 15, qd = lane >> 4;
    short8 af[8];
#pragma unroll
    for (int mt = 0; mt < 4; mt++)
#pragma unroll
        for (int kf = 0; kf < 2; kf++)
            af[mt * 2 + kf] = *(const short8*)&xA[((mt * 2 + kf) * 64 + lane) * 8];

    int n0 = head * 16;
    const unsigned short* wp = proj_wb + (size_t)(n0 + nh) * 64 + qd * 8;
    short8 b0 = *(const short8*)(wp);
    short8 b1 = *(const short8*)(wp + 32);
    float bias = proj_b[n0 + nh];
#pragma unroll
    for (int mt = 0; mt < 4; mt++) {
        f32x4 d = {0.f, 0.f, 0.f, 0.f};
        d = __builtin_amdgcn_mfma_f32_16x16x32_bf16(af[mt * 2 + 0], b0, d, 0, 0, 0);
        d = __builtin_amdgcn_mfma_f32_16x16x32_bf16(af[mt * 2 + 1], b1, d, 0, 0, 0);
#pragma unroll
        for (int r = 0; r < 4; r++)
            obuf[head][nh * 65 + mt * 16 + qd * 4 + r] = d[r] + bias;
    }
    __syncthreads();

    // transpose-out + x residual, store y4 fp32
    const float* xr = x + n * PER_SAMPLE + h * 64;
#pragma unroll
    for (int u = 0; u < 4; u++) {
        int cg = (n0 >> 2) + u;
        float4 o;
        o.x = obuf[head][(u * 4 + 0) * 65 + lane] + xr[(size_t)(cg * 4 + 0) * SPATIAL + lane];
        o.y = obuf[head][(u * 4 + 1) * 65 + lane] + xr[(size_t)(cg * 4 + 1) * SPATIAL + lane];
        o.z = obuf[head][(u * 4 + 2) * 65 + lane] + xr[(size_t)(cg * 4 + 2) * SPATIAL + lane];
        o.w = obuf[head][(u * 4 + 3) * 65 + lane] + xr[(size_t)(cg * 4 + 3) * SPATIAL + lane];
        y4[(size_t)cg * NTOK + rowbase + lane] = o;
    }
}

// ---------------- K4: LN + fc1 + GELU + fc2 + residual via MFMA (unchanged) ----------------
__global__ __launch_bounds__(256) void k_mlp(const float4* __restrict__ y4,
                                             const float* __restrict__ ln_w,
                                             const float* __restrict__ ln_b,
                                             const unsigned short* __restrict__ fc1_wb,
                                             const float* __restrict__ fc1_b,
                                             const unsigned short* __restrict__ fc2_wb,
                                             const float* __restrict__ fc2_b,
                                             float* __restrict__ out) {
    __shared__ __attribute__((aligned(16))) short ynA[4 * 2 * 64 * 8];  // 8 KB
    __shared__ __attribute__((aligned(16))) short lhA[4 * 8 * 64 * 8];  // 32 KB
    __shared__ float obuf[4][16 * 65];
    __shared__ float red1[256], red2[256];
    int s0 = blockIdx.x * 64;
    int smp = s0 >> 12, sp = s0 & 4095;
    int t = threadIdx.x, tok = t & 63, g = t >> 6;

    float v[16];
    float s1 = 0.f, s2 = 0.f;
#pragma unroll
    for (int i = 0; i < 4; i++) {
        float4 yy = y4[(size_t)(g * 4 + i) * NTOK + s0 + tok];
        v[i * 4 + 0] = yy.x; v[i * 4 + 1] = yy.y; v[i * 4 + 2] = yy.z; v[i * 4 + 3] = yy.w;
        s1 += yy.x + yy.y + yy.z + yy.w;
        s2 += yy.x * yy.x + yy.y * yy.y + yy.z * yy.z + yy.w * yy.w;
    }
    red1[g * 64 + tok] = s1;
    red2[g * 64 + tok] = s2;
    __syncthreads();
    float mu = (red1[tok] + red1[64 + tok] + red1[128 + tok] + red1[192 + tok]) * (1.f / 64.f);
    float sq = (red2[tok] + red2[64 + tok] + red2[128 + tok] + red2[192 + tok]) * (1.f / 64.f);
    float rstd = rsqrtf(sq - mu * mu + EPS);
#pragma unroll
    for (int i = 0; i < 16; i++) {
        int c = g * 16 + i;
        v[i] = (v[i] - mu) * rstd * ln_w[c] + ln_b[c];
    }
#pragma unroll
    for (int e = 0; e < 2; e++) {
        int cb = 2 * g + e;
        int kf = cb >> 2, qq = cb & 3;
        uint4 p;
        p.x = pack2(v[e * 8 + 0], v[e * 8 + 1]);
        p.y = pack2(v[e * 8 + 2], v[e * 8 + 3]);
        p.z = pack2(v[e * 8 + 4], v[e * 8 + 5]);
        p.w = pack2(v[e * 8 + 6], v[e * 8 + 7]);
        int chunk = ((tok >> 4) * 2 + kf) * 64 + (tok & 15) + (qq << 4);
        *(uint4*)&ynA[chunk * 8] = p;
    }
    __syncthreads();

    int w = __builtin_amdgcn_readfirstlane(g);
    int lane = t & 63, nh = lane & 15, q = lane >> 4;

    {
        short8 af[8];
#pragma unroll
        for (int mt = 0; mt < 4; mt++)
#pragma unroll
            for (int kf = 0; kf < 2; kf++)
                af[mt * 2 + kf] = *(const short8*)&ynA[((mt * 2 + kf) * 64 + lane) * 8];

        for (int nt = 0; nt < 4; nt++) {
            int n0 = w * 64 + nt * 16;
            const unsigned short* wp = fc1_wb + (size_t)(n0 + nh) * 64 + q * 8;
            short8 b0 = *(const short8*)(wp);
            short8 b1 = *(const short8*)(wp + 32);
            float bias = fc1_b[n0 + nh];
            int j = n0 + nh;
            int kf2 = j >> 5, q2 = (j >> 3) & 3, jb = j & 7;
#pragma unroll
            for (int mt = 0; mt < 4; mt++) {
                f32x4 d = {0.f, 0.f, 0.f, 0.f};
                d = __builtin_amdgcn_mfma_f32_16x16x32_bf16(af[mt * 2 + 0], b0, d, 0, 0, 0);
                d = __builtin_amdgcn_mfma_f32_16x16x32_bf16(af[mt * 2 + 1], b1, d, 0, 0, 0);
#pragma unroll
                for (int r = 0; r < 4; r++) {
                    float hv = d[r] + bias;
                    hv = 0.5f * hv * (1.f + erff(hv * 0.70710678118654752f));
                    lhA[(mt * 8 + kf2) * 512 + ((q * 4 + r) + (q2 << 4)) * 8 + jb] = (short)f2bf(hv);
                }
            }
        }
    }
    __syncthreads();

    {
        int n0 = w * 16;
        f32x4 acc[4];
#pragma unroll
        for (int mt = 0; mt < 4; mt++) acc[mt] = (f32x4){0.f, 0.f, 0.f, 0.f};
#pragma unroll
        for (int kf = 0; kf < 8; kf++) {
            const unsigned short* wp = fc2_wb + (size_t)(n0 + nh) * 256 + kf * 32 + q * 8;
            short8 b = *(const short8*)(wp);
#pragma unroll
            for (int mt = 0; mt < 4; mt++) {
                short8 a = *(const short8*)&lhA[((mt * 8 + kf) * 64 + lane) * 8];
                acc[mt] = __builtin_amdgcn_mfma_f32_16x16x32_bf16(a, b, acc[mt], 0, 0, 0);
            }
        }
#pragma unroll
        for (int mt = 0; mt < 4; mt++)
#pragma unroll
            for (int r = 0; r < 4; r++)
                obuf[w][nh * 65 + mt * 16 + q * 4 + r] = acc[mt][r];
        __syncthreads();

        float* op = out + (size_t)smp * PER_SAMPLE + sp;
#pragma unroll
        for (int u = 0; u < 4; u++) {
            int cg = (n0 >> 2) + u;
            float4 res = y4[(size_t)cg * NTOK + s0 + lane];
            float rr[4] = {res.x, res.y, res.z, res.w};
#pragma unroll
            for (int e = 0; e < 4; e++) {
                int c = cg * 4 + e;
                op[(size_t)c * SPATIAL + lane] = obuf[w][(u * 4 + e) * 65 + lane] + fc2_b[c] + rr[e];
            }
        }
    }
}

extern "C" void kernel_launch(void* const* d_in, const int* in_sizes, int n_in,
                              void* d_out, int out_size, void* d_ws, size_t ws_size,
                              hipStream_t stream) {
    const float* x      = (const float*)d_in[0];
    const float* gn_w   = (const float*)d_in[1];
    const float* gn_b   = (const float*)d_in[2];
    const float* qkv_w  = (const float*)d_in[3];
    const float* qkv_b  = (const float*)d_in[4];
    const float* rpb    = (const float*)d_in[5];
    const float* proj_w = (const float*)d_in[6];
    const float* proj_b = (const float*)d_in[7];
    const float* ln_w   = (const float*)d_in[8];
    const float* ln_b   = (const float*)d_in[9];
    const float* fc1_w  = (const float*)d_in[10];
    const float* fc1_b  = (const float*)d_in[11];
    const float* fc2_w  = (const float*)d_in[12];
    const float* fc2_b  = (const float*)d_in[13];
    float* out = (float*)d_out;

    float* ws    = (float*)d_ws;
    float* stats = ws;                                      // 64 floats
    uint4* qb8   = (uint4*)(ws + 64);                       // 8  * NTOK uint4 = 4.2 MB
    uint4* kvb8  = qb8 + (size_t)8 * NTOK;                  // 16 * NTOK uint4 = 8.4 MB
    float4* y4   = (float4*)(kvb8 + (size_t)16 * NTOK);     // 16 * NTOK float4 = 8.4 MB
    unsigned short* wb = (unsigned short*)(y4 + (size_t)16 * NTOK);  // 49152 bf16
    unsigned short* qkv_wb  = wb;
    unsigned short* fc1_wb  = wb + 12288;
    unsigned short* fc2_wb  = wb + 28672;
    unsigned short* proj_wb = wb + 45056;

    hipMemsetAsync(stats, 0, 64, stream);
    k_prep    <<<192, 256, 0, stream>>>(qkv_w, fc1_w, fc2_w, proj_w, wb);
    k_stats   <<<256, 256, 0, stream>>>(x, stats);
    k_qkv     <<<512, 256, 0, stream>>>(x, stats, gn_w, gn_b, qkv_wb, qkv_b, qb8, kvb8);
    k_attnproj<<<512, 256, 0, stream>>>(qb8, kvb8, rpb, proj_wb, proj_b, x, y4);
    k_mlp     <<<512, 256, 0, stream>>>(y4, ln_w, ln_b, fc1_wb, fc1_b, fc2_wb, fc2_b, out);
}

// Round 7
// 132.048 us; speedup vs baseline: 2.5107x; 1.0413x over previous
//
#include <hip/hip_runtime.h>
#include <math.h>

#define NSAMP 8
#define CH 64
#define HH 64
#define WW 64
#define SPATIAL 4096        // HH*WW
#define PER_SAMPLE 262144   // CH*SPATIAL
#define NTOK 32768          // NSAMP*SPATIAL
#define NHEADS 4
#define HD 16
#define KS 7
#define EPS 1e-5f
#define QSCALE 0.25f        // HD^-0.5

typedef __attribute__((ext_vector_type(8))) short short8;
typedef __attribute__((ext_vector_type(4))) float f32x4;

__device__ __forceinline__ unsigned short f2bf(float f) {
    unsigned u = __float_as_uint(f);
    u = u + 0x7fffu + ((u >> 16) & 1u);     // round-to-nearest-even
    return (unsigned short)(u >> 16);
}
__device__ __forceinline__ unsigned pack2(float a, float b) {
    return (unsigned)f2bf(a) | ((unsigned)f2bf(b) << 16);
}
__device__ __forceinline__ float dot8_bf(uint4 u, const float* qv) {
    float s;
    s = __uint_as_float(u.x << 16) * qv[0];
    s = fmaf(__uint_as_float(u.x & 0xffff0000u), qv[1], s);
    s = fmaf(__uint_as_float(u.y << 16),         qv[2], s);
    s = fmaf(__uint_as_float(u.y & 0xffff0000u), qv[3], s);
    s = fmaf(__uint_as_float(u.z << 16),         qv[4], s);
    s = fmaf(__uint_as_float(u.z & 0xffff0000u), qv[5], s);
    s = fmaf(__uint_as_float(u.w << 16),         qv[6], s);
    s = fmaf(__uint_as_float(u.w & 0xffff0000u), qv[7], s);
    return s;
}
__device__ __forceinline__ void pv8_bf(uint4 u, float p, float* acc) {
    acc[0] = fmaf(p, __uint_as_float(u.x << 16),         acc[0]);
    acc[1] = fmaf(p, __uint_as_float(u.x & 0xffff0000u), acc[1]);
    acc[2] = fmaf(p, __uint_as_float(u.y << 16),         acc[2]);
    acc[3] = fmaf(p, __uint_as_float(u.y & 0xffff0000u), acc[3]);
    acc[4] = fmaf(p, __uint_as_float(u.z << 16),         acc[4]);
    acc[5] = fmaf(p, __uint_as_float(u.z & 0xffff0000u), acc[5]);
    acc[6] = fmaf(p, __uint_as_float(u.w << 16),         acc[6]);
    acc[7] = fmaf(p, __uint_as_float(u.w & 0xffff0000u), acc[7]);
}

// ---------------- K1: per-sample sum/sumsq (blocks 0-255) + weight->bf16 (blocks 256-447) ----------------
__global__ __launch_bounds__(256) void k_statsprep(const float* __restrict__ x,
                                                   float* __restrict__ stats,
                                                   const float* __restrict__ qkv_w,
                                                   const float* __restrict__ fc1_w,
                                                   const float* __restrict__ fc2_w,
                                                   const float* __restrict__ proj_w,
                                                   unsigned short* __restrict__ wb) {
    int blk = blockIdx.x;
    if (blk >= 256) {           // prep: 192 blocks x 256 = 49152 weights
        int i = (blk - 256) * 256 + threadIdx.x;
        if (i < 12288)      wb[i] = f2bf(qkv_w[i]);
        else if (i < 28672) wb[i] = f2bf(fc1_w[i - 12288]);
        else if (i < 45056) wb[i] = f2bf(fc2_w[i - 28672]);
        else                wb[i] = f2bf(proj_w[i - 45056]);
        return;
    }
    int n = blk >> 5, chunk = blk & 31;
    const float4* p4 = (const float4*)(x + n * PER_SAMPLE + chunk * 8192);
    int t = threadIdx.x;
    float s1 = 0.f, s2 = 0.f;
#pragma unroll
    for (int i = 0; i < 8; i++) {
        float4 v = p4[t + i * 256];
        s1 += v.x + v.y + v.z + v.w;
        s2 += v.x * v.x + v.y * v.y + v.z * v.z + v.w * v.w;
    }
#pragma unroll
    for (int off = 1; off < 64; off <<= 1) {
        s1 += __shfl_xor(s1, off);
        s2 += __shfl_xor(s2, off);
    }
    __shared__ float r1[4], r2[4];
    int lane = t & 63, wv = t >> 6;
    if (lane == 0) { r1[wv] = s1; r2[wv] = s2; }
    __syncthreads();
    if (t == 0) {
        atomicAdd(&stats[n * 2 + 0], r1[0] + r1[1] + r1[2] + r1[3]);
        atomicAdd(&stats[n * 2 + 1], r2[0] + r2[1] + r2[2] + r2[3]);
    }
}

// ---------------- K2: GN + QKV GEMM via MFMA -> bf16 q / kv ----------------
__global__ __launch_bounds__(256) void k_qkv(const float* __restrict__ x,
                                             const float* __restrict__ stats,
                                             const float* __restrict__ gn_w,
                                             const float* __restrict__ gn_b,
                                             const unsigned short* __restrict__ qkv_wb,
                                             const float* __restrict__ qkv_b,
                                             uint4* __restrict__ qb8,
                                             uint4* __restrict__ kvb8) {
    __shared__ __attribute__((aligned(16))) short xA[4 * 2 * 64 * 8];  // 8 KB frag-major A
    __shared__ float obuf[4][16 * 65];                                 // per-wave transpose
    int s0 = blockIdx.x * 64;
    int smp = s0 >> 12, sp = s0 & 4095;
    int t = threadIdx.x, tok = t & 63, g = t >> 6;

    float mu = stats[2 * smp] * (1.f / (float)PER_SAMPLE);
    float var = stats[2 * smp + 1] * (1.f / (float)PER_SAMPLE) - mu * mu;
    float rstd = rsqrtf(var + EPS);

    {
        const float* xp = x + smp * PER_SAMPLE + sp + tok;
        float v[16];
#pragma unroll
        for (int i = 0; i < 16; i++) {
            int c = g * 16 + i;
            v[i] = (xp[(size_t)c * SPATIAL] - mu) * rstd * gn_w[c] + gn_b[c];
        }
#pragma unroll
        for (int e = 0; e < 2; e++) {
            int cb = 2 * g + e;
            int kf = cb >> 2, qq = cb & 3;
            uint4 p;
            p.x = pack2(v[e * 8 + 0], v[e * 8 + 1]);
            p.y = pack2(v[e * 8 + 2], v[e * 8 + 3]);
            p.z = pack2(v[e * 8 + 4], v[e * 8 + 5]);
            p.w = pack2(v[e * 8 + 6], v[e * 8 + 7]);
            int chunk = ((tok >> 4) * 2 + kf) * 64 + (tok & 15) + (qq << 4);
            *(uint4*)&xA[chunk * 8] = p;
        }
    }
    __syncthreads();

    int w = __builtin_amdgcn_readfirstlane(g);
    int lane = t & 63, nh = lane & 15, qd = lane >> 4;

    short8 af[8];
#pragma unroll
    for (int mt = 0; mt < 4; mt++)
#pragma unroll
        for (int kf = 0; kf < 2; kf++)
            af[mt * 2 + kf] = *(const short8*)&xA[((mt * 2 + kf) * 64 + lane) * 8];

    for (int nt = 0; nt < 3; nt++) {
        int n0 = w * 48 + nt * 16;
        const unsigned short* wp = qkv_wb + (size_t)(n0 + nh) * 64 + qd * 8;
        short8 b0 = *(const short8*)(wp);
        short8 b1 = *(const short8*)(wp + 32);
        float bias = qkv_b[n0 + nh];
        bool isq = (n0 < 64);
        f32x4 acc[4];
#pragma unroll
        for (int mt = 0; mt < 4; mt++) {
            f32x4 d = {0.f, 0.f, 0.f, 0.f};
            d = __builtin_amdgcn_mfma_f32_16x16x32_bf16(af[mt * 2 + 0], b0, d, 0, 0, 0);
            d = __builtin_amdgcn_mfma_f32_16x16x32_bf16(af[mt * 2 + 1], b1, d, 0, 0, 0);
            acc[mt] = d;
        }
#pragma unroll
        for (int mt = 0; mt < 4; mt++)
#pragma unroll
            for (int r = 0; r < 4; r++) {
                float vv = acc[mt][r] + bias;
                if (isq) vv *= QSCALE;
                obuf[w][nh * 65 + mt * 16 + qd * 4 + r] = vv;
            }
        __builtin_amdgcn_wave_barrier();     // obuf is per-wave; DS in-order per wave
#pragma unroll
        for (int u = 0; u < 2; u++) {
            uint4 p;
            p.x = pack2(obuf[w][(u * 8 + 0) * 65 + lane], obuf[w][(u * 8 + 1) * 65 + lane]);
            p.y = pack2(obuf[w][(u * 8 + 2) * 65 + lane], obuf[w][(u * 8 + 3) * 65 + lane]);
            p.z = pack2(obuf[w][(u * 8 + 4) * 65 + lane], obuf[w][(u * 8 + 5) * 65 + lane]);
            p.w = pack2(obuf[w][(u * 8 + 6) * 65 + lane], obuf[w][(u * 8 + 7) * 65 + lane]);
            if (n0 < 64)
                qb8[(size_t)((n0 >> 3) + u) * NTOK + s0 + lane] = p;
            else if (n0 < 128)
                kvb8[(size_t)(((n0 - 64) >> 3) + u) * NTOK + s0 + lane] = p;
            else
                kvb8[(size_t)(8 + ((n0 - 128) >> 3) + u) * NTOK + s0 + lane] = p;
        }
        __builtin_amdgcn_wave_barrier();     // before next nt rewrites obuf[w]
    }
}

// ---------------- K3: attention + proj + LN + MLP + residuals, fully fused ----------------
// 512 blocks x 256 threads; block = (sample,row) = 64 tokens; wave g = head/group, lane = col/tok
__global__ __launch_bounds__(256) void k_fused(const uint4* __restrict__ qb8,
                                               const uint4* __restrict__ kvb8,
                                               const float* __restrict__ rpb,
                                               const unsigned short* __restrict__ proj_wb,
                                               const float* __restrict__ proj_b,
                                               const float* __restrict__ x,
                                               const float* __restrict__ ln_w,
                                               const float* __restrict__ ln_b,
                                               const unsigned short* __restrict__ fc1_wb,
                                               const float* __restrict__ fc1_b,
                                               const unsigned short* __restrict__ fc2_wb,
                                               const float* __restrict__ fc2_b,
                                               float* __restrict__ out) {
    __shared__ __attribute__((aligned(16))) short fragA[4 * 2 * 64 * 8];  // 8 KB (attn-out, then yn)
    __shared__ __attribute__((aligned(16))) short lhA[4 * 4 * 64 * 8];    // 16 KB (half of hidden)
    __shared__ float obuf[4][16 * 65];                                    // 16.6 KB
    __shared__ float ybuf[64 * 65];                                       // 16.6 KB (y = attn+proj+x)
    __shared__ float red1[256], red2[256];                                // 2 KB
    int b = blockIdx.x, n = b >> 6, h = b & 63;
    int t = threadIdx.x, w = t & 63;
    int g = __builtin_amdgcn_readfirstlane(t >> 6);
    int rowbase = n * 4096 + h * 64;

    // ---- neighborhood attention (g = head) ----
    float q[16];
    {
        uint4 qa = qb8[(size_t)(2 * g) * NTOK + rowbase + w];
        uint4 qc = qb8[(size_t)(2 * g + 1) * NTOK + rowbase + w];
        q[0] = __uint_as_float(qa.x << 16); q[1] = __uint_as_float(qa.x & 0xffff0000u);
        q[2] = __uint_as_float(qa.y << 16); q[3] = __uint_as_float(qa.y & 0xffff0000u);
        q[4] = __uint_as_float(qa.z << 16); q[5] = __uint_as_float(qa.z & 0xffff0000u);
        q[6] = __uint_as_float(qa.w << 16); q[7] = __uint_as_float(qa.w & 0xffff0000u);
        q[8]  = __uint_as_float(qc.x << 16); q[9]  = __uint_as_float(qc.x & 0xffff0000u);
        q[10] = __uint_as_float(qc.y << 16); q[11] = __uint_as_float(qc.y & 0xffff0000u);
        q[12] = __uint_as_float(qc.z << 16); q[13] = __uint_as_float(qc.z & 0xffff0000u);
        q[14] = __uint_as_float(qc.w << 16); q[15] = __uint_as_float(qc.w & 0xffff0000u);
    }
    int sh = min(max(h - 3, 0), HH - KS);
    int sw = min(max(w - 3, 0), WW - KS);

    float lg[49];
    float mx = -1e30f;
#pragma unroll
    for (int a = 0; a < 7; a++) {
        int nb = n * 4096 + (sh + a) * 64 + sw;
        const float* rp = rpb + (g * 13 + (h - sh + 6 - a)) * 13;
#pragma unroll
        for (int bb = 0; bb < 7; bb++) {
            size_t base = (size_t)(2 * g) * NTOK + nb + bb;
            float d = dot8_bf(kvb8[base], q) + dot8_bf(kvb8[base + NTOK], q + 8);
            d += rp[w - sw + 6 - bb];
            lg[a * 7 + bb] = d;
            mx = fmaxf(mx, d);
        }
    }
    float sum = 0.f;
#pragma unroll
    for (int i = 0; i < 49; i++) {
        float e = __expf(lg[i] - mx);
        lg[i] = e;
        sum += e;
    }
    float rs = 1.f / sum;

    float acc[16];
#pragma unroll
    for (int i = 0; i < 16; i++) acc[i] = 0.f;
#pragma unroll
    for (int a = 0; a < 7; a++) {
        int nb = n * 4096 + (sh + a) * 64 + sw;
#pragma unroll
        for (int bb = 0; bb < 7; bb++) {
            size_t base = (size_t)(8 + 2 * g) * NTOK + nb + bb;
            float p = lg[a * 7 + bb];
            pv8_bf(kvb8[base], p, acc);
            pv8_bf(kvb8[base + NTOK], p, acc + 8);
        }
    }
    // stage attn-out (x rs) as bf16 A-frags
#pragma unroll
    for (int e = 0; e < 2; e++) {
        int cb = 2 * g + e;
        int kf = cb >> 2, qq = cb & 3;
        uint4 p;
        p.x = pack2(acc[e * 8 + 0] * rs, acc[e * 8 + 1] * rs);
        p.y = pack2(acc[e * 8 + 2] * rs, acc[e * 8 + 3] * rs);
        p.z = pack2(acc[e * 8 + 4] * rs, acc[e * 8 + 5] * rs);
        p.w = pack2(acc[e * 8 + 6] * rs, acc[e * 8 + 7] * rs);
        int chunk = ((w >> 4) * 2 + kf) * 64 + (w & 15) + (qq << 4);
        *(uint4*)&fragA[chunk * 8] = p;
    }
    __syncthreads();                                    // B1

    int lane = t & 63, nh = lane & 15, qd = lane >> 4;
    // ---- proj MFMA -> ybuf (+x residual) ----
    {
        short8 af[8];
#pragma unroll
        for (int mt = 0; mt < 4; mt++)
#pragma unroll
            for (int kf = 0; kf < 2; kf++)
                af[mt * 2 + kf] = *(const short8*)&fragA[((mt * 2 + kf) * 64 + lane) * 8];

        int n0 = g * 16;
        const unsigned short* wp = proj_wb + (size_t)(n0 + nh) * 64 + qd * 8;
        short8 b0 = *(const short8*)(wp);
        short8 b1 = *(const short8*)(wp + 32);
        float bias = proj_b[n0 + nh];
#pragma unroll
        for (int mt = 0; mt < 4; mt++) {
            f32x4 d = {0.f, 0.f, 0.f, 0.f};
            d = __builtin_amdgcn_mfma_f32_16x16x32_bf16(af[mt * 2 + 0], b0, d, 0, 0, 0);
            d = __builtin_amdgcn_mfma_f32_16x16x32_bf16(af[mt * 2 + 1], b1, d, 0, 0, 0);
#pragma unroll
            for (int r = 0; r < 4; r++)
                obuf[g][nh * 65 + mt * 16 + qd * 4 + r] = d[r] + bias;
        }
        __builtin_amdgcn_wave_barrier();
        const float* xr = x + n * PER_SAMPLE + h * 64;
#pragma unroll
        for (int u = 0; u < 4; u++) {
#pragma unroll
            for (int e = 0; e < 4; e++) {
                int c = g * 16 + u * 4 + e;
                ybuf[c * 65 + lane] = obuf[g][(u * 4 + e) * 65 + lane]
                                    + xr[(size_t)c * SPATIAL + lane];
            }
        }
    }
    __syncthreads();                                    // B2

    // ---- LN -> fragA (yn A-frags) ----
    {
        float v[16];
        float s1 = 0.f, s2 = 0.f;
#pragma unroll
        for (int i = 0; i < 16; i++) {
            float vv = ybuf[(g * 16 + i) * 65 + w];
            v[i] = vv; s1 += vv; s2 += vv * vv;
        }
        red1[g * 64 + w] = s1;
        red2[g * 64 + w] = s2;
        __syncthreads();                                // B3
        float mu = (red1[w] + red1[64 + w] + red1[128 + w] + red1[192 + w]) * (1.f / 64.f);
        float sq = (red2[w] + red2[64 + w] + red2[128 + w] + red2[192 + w]) * (1.f / 64.f);
        float rstd = rsqrtf(sq - mu * mu + EPS);
#pragma unroll
        for (int i = 0; i < 16; i++) {
            int c = g * 16 + i;
            v[i] = (v[i] - mu) * rstd * ln_w[c] + ln_b[c];
        }
#pragma unroll
        for (int e = 0; e < 2; e++) {
            int cb = 2 * g + e;
            int kf = cb >> 2, qq = cb & 3;
            uint4 p;
            p.x = pack2(v[e * 8 + 0], v[e * 8 + 1]);
            p.y = pack2(v[e * 8 + 2], v[e * 8 + 3]);
            p.z = pack2(v[e * 8 + 4], v[e * 8 + 5]);
            p.w = pack2(v[e * 8 + 6], v[e * 8 + 7]);
            int chunk = ((w >> 4) * 2 + kf) * 64 + (w & 15) + (qq << 4);
            *(uint4*)&fragA[chunk * 8] = p;
        }
    }
    __syncthreads();                                    // B4

    // ---- fc1 + GELU + fc2 in two K=128 halves ----
    short8 yf[8];
#pragma unroll
    for (int mt = 0; mt < 4; mt++)
#pragma unroll
        for (int kf = 0; kf < 2; kf++)
            yf[mt * 2 + kf] = *(const short8*)&fragA[((mt * 2 + kf) * 64 + lane) * 8];

    f32x4 acc2[4];
#pragma unroll
    for (int mt = 0; mt < 4; mt++) acc2[mt] = (f32x4){0.f, 0.f, 0.f, 0.f};

    for (int half = 0; half < 2; half++) {
#pragma unroll
        for (int nt = 0; nt < 2; nt++) {
            int n0f = half * 128 + g * 32 + nt * 16;
            const unsigned short* wp = fc1_wb + (size_t)(n0f + nh) * 64 + qd * 8;
            short8 b0 = *(const short8*)(wp);
            short8 b1 = *(const short8*)(wp + 32);
            float bias = fc1_b[n0f + nh];
            int j = n0f + nh;
            int kfl = (j - half * 128) >> 5;
            int q2 = (j >> 3) & 3, jb = j & 7;
#pragma unroll
            for (int mt = 0; mt < 4; mt++) {
                f32x4 d = {0.f, 0.f, 0.f, 0.f};
                d = __builtin_amdgcn_mfma_f32_16x16x32_bf16(yf[mt * 2 + 0], b0, d, 0, 0, 0);
                d = __builtin_amdgcn_mfma_f32_16x16x32_bf16(yf[mt * 2 + 1], b1, d, 0, 0, 0);
#pragma unroll
                for (int r = 0; r < 4; r++) {
                    float hv = d[r] + bias;
                    hv = 0.5f * hv * (1.f + erff(hv * 0.70710678118654752f));
                    lhA[(mt * 4 + kfl) * 512 + ((qd * 4 + r) + (q2 << 4)) * 8 + jb] = (short)f2bf(hv);
                }
            }
        }
        __syncthreads();                                // B5 / B7
#pragma unroll
        for (int kf = 0; kf < 4; kf++) {
            int kfg = half * 4 + kf;
            const unsigned short* wp = fc2_wb + (size_t)(g * 16 + nh) * 256 + kfg * 32 + qd * 8;
            short8 bb = *(const short8*)(wp);
#pragma unroll
            for (int mt = 0; mt < 4; mt++) {
                short8 a = *(const short8*)&lhA[((mt * 4 + kf) * 64 + lane) * 8];
                acc2[mt] = __builtin_amdgcn_mfma_f32_16x16x32_bf16(a, bb, acc2[mt], 0, 0, 0);
            }
        }
        __syncthreads();                                // B6 / B8 (before lhA reuse)
    }

    // ---- epilogue: transpose, + fc2_b + y residual, NCHW coalesced store ----
#pragma unroll
    for (int mt = 0; mt < 4; mt++)
#pragma unroll
        for (int r = 0; r < 4; r++)
            obuf[g][nh * 65 + mt * 16 + qd * 4 + r] = acc2[mt][r];
    __builtin_amdgcn_wave_barrier();
    float* op = out + (size_t)n * PER_SAMPLE + h * 64;
#pragma unroll
    for (int u = 0; u < 4; u++) {
#pragma unroll
        for (int e = 0; e < 4; e++) {
            int c = g * 16 + u * 4 + e;
            op[(size_t)c * SPATIAL + lane] = obuf[g][(u * 4 + e) * 65 + lane]
                                           + fc2_b[c] + ybuf[c * 65 + lane];
        }
    }
}

extern "C" void kernel_launch(void* const* d_in, const int* in_sizes, int n_in,
                              void* d_out, int out_size, void* d_ws, size_t ws_size,
                              hipStream_t stream) {
    const float* x      = (const float*)d_in[0];
    const float* gn_w   = (const float*)d_in[1];
    const float* gn_b   = (const float*)d_in[2];
    const float* qkv_w  = (const float*)d_in[3];
    const float* qkv_b  = (const float*)d_in[4];
    const float* rpb    = (const float*)d_in[5];
    const float* proj_w = (const float*)d_in[6];
    const float* proj_b = (const float*)d_in[7];
    const float* ln_w   = (const float*)d_in[8];
    const float* ln_b   = (const float*)d_in[9];
    const float* fc1_w  = (const float*)d_in[10];
    const float* fc1_b  = (const float*)d_in[11];
    const float* fc2_w  = (const float*)d_in[12];
    const float* fc2_b  = (const float*)d_in[13];
    float* out = (float*)d_out;

    float* ws    = (float*)d_ws;
    float* stats = ws;                                      // 64 floats
    uint4* qb8   = (uint4*)(ws + 64);                       // 8  * NTOK uint4 = 4.2 MB
    uint4* kvb8  = qb8 + (size_t)8 * NTOK;                  // 16 * NTOK uint4 = 8.4 MB
    unsigned short* wb = (unsigned short*)(kvb8 + (size_t)16 * NTOK);  // 49152 bf16
    unsigned short* qkv_wb  = wb;
    unsigned short* fc1_wb  = wb + 12288;
    unsigned short* fc2_wb  = wb + 28672;
    unsigned short* proj_wb = wb + 45056;

    hipMemsetAsync(stats, 0, 64, stream);
    k_statsprep<<<448, 256, 0, stream>>>(x, stats, qkv_w, fc1_w, fc2_w, proj_w, wb);
    k_qkv      <<<512, 256, 0, stream>>>(x, stats, gn_w, gn_b, qkv_wb, qkv_b, qb8, kvb8);
    k_fused    <<<512, 256, 0, stream>>>(qb8, kvb8, rpb, proj_wb, proj_b, x,
                                         ln_w, ln_b, fc1_wb, fc1_b, fc2_wb, fc2_b, out);
}